// Round 1
// baseline (7266.055 us; speedup 1.0000x reference)
//
#include <hip/hip_runtime.h>
#include <cstdint>

typedef short short8  __attribute__((ext_vector_type(8)));
typedef unsigned short ushort4v __attribute__((ext_vector_type(4)));
typedef float floatx4 __attribute__((ext_vector_type(4)));

#define HID    128
#define NB     32
#define TPB    256
#define NBLK   2048          // 65536 / 32
#define TSTEPS 30
#define MU_OFF 5898240       // 65536*30*3

// ws layout (bf16 units): A-fragment-swizzled weight arrays, hi then lo per set
#define L0_SZ  81920         // 512*160  (K-ext: [Whh(128)|Wih0(3)|0(29)])
#define L1_SZ  131072        // 512*256  (K-ext: [Wih1(128)|Whh1(128)])
#define ENC0_HI 0
#define ENC0_LO 81920
#define ENC1_HI 163840
#define ENC1_LO 294912
#define DEC0_HI 425984
#define DEC0_LO 507904
#define DEC1_HI 589824
#define DEC1_LO 720896

#define S0 128               // h0 row stride (bf16): 16 k-blocks (x lives in xbuf now)
#define S1 128               // h1 row stride: 16 k-blocks

// v_rcp_f32 (~1 ulp) instead of the IEEE div chain (~10 instrs without fast-math)
__device__ __forceinline__ float sigm(float v){
  return __builtin_amdgcn_rcpf(1.f + __expf(-v));
}
__device__ __forceinline__ float tanh_fast(float v){
  return 2.f*__builtin_amdgcn_rcpf(1.f + __expf(-2.f*v)) - 1.f;
}

__device__ __forceinline__ unsigned short f2bf(float f){
  unsigned u = __float_as_uint(f);
  u = (u + 0x7FFF + ((u>>16)&1)) >> 16;     // RNE; inputs finite
  return (unsigned short)u;
}
__device__ __forceinline__ float bf2f(unsigned short b){
  return __uint_as_float(((unsigned)b)<<16);
}

// ---------------- prep: swizzle weights into A-fragment order, bf16 hi/lo ----
// A-frag element (mt, kt, lane l, jj):  A[mt*16 + (l&15)][kt*32 + ((l>>4)&3)*8 + jj]
// stored at ((mt*KT + kt)*64 + l)*8 + jj   -> consumer does 1 coalesced b128/lane
extern "C" __global__ void __launch_bounds__(256)
prep_frag(const float* __restrict__ eWih0, const float* __restrict__ eWhh0,
          const float* __restrict__ eWih1, const float* __restrict__ eWhh1,
          const float* __restrict__ dWih0, const float* __restrict__ dWhh0,
          const float* __restrict__ dWih1, const float* __restrict__ dWhh1,
          unsigned short* __restrict__ ws)
{
  const int idx = blockIdx.x*256 + threadIdx.x;   // one thread -> one (hi,lo) pair
  int i2, hi_base, lo_base, KT;
  const float* Wa; const float* Wb;
  if (idx < L0_SZ)                { i2=idx;                 hi_base=ENC0_HI; lo_base=ENC0_LO; Wa=eWhh0; Wb=eWih0; KT=5; }
  else if (idx < L0_SZ+L1_SZ)     { i2=idx-L0_SZ;           hi_base=ENC1_HI; lo_base=ENC1_LO; Wa=eWih1; Wb=eWhh1; KT=8; }
  else if (idx < 2*L0_SZ+L1_SZ)   { i2=idx-(L0_SZ+L1_SZ);   hi_base=DEC0_HI; lo_base=DEC0_LO; Wa=dWhh0; Wb=dWih0; KT=5; }
  else                            { i2=idx-(2*L0_SZ+L1_SZ); hi_base=DEC1_HI; lo_base=DEC1_LO; Wa=dWih1; Wb=dWhh1; KT=8; }
  const int jj = i2 & 7, l = (i2>>3)&63, tk = i2>>9;
  const int kt = (KT==5) ? (tk%5) : (tk&7);
  const int mt = (KT==5) ? (tk/5) : (tk>>3);
  const int row = mt*16 + (l&15);
  const int k   = kt*32 + ((l>>4)&3)*8 + jj;
  float w;
  if (KT==5) w = (k<128) ? Wa[row*128+k] : ((k<131) ? Wb[row*3 + (k-128)] : 0.f);
  else       w = (k<128) ? Wa[row*128+k] : Wb[row*128 + (k-128)];
  const unsigned short hi = f2bf(w);
  ws[hi_base + i2] = hi;
  ws[lo_base + i2] = f2bf(w - bf2f(hi));
}

// ---------------- fused LSTM: NB=32/block, 4 waves, 4 blocks/CU target ------
extern "C" __global__ void __launch_bounds__(TPB, 4)
lstm_mfma(const float* __restrict__ x,
          const unsigned short* __restrict__ wf,
          const float* __restrict__ enc_b0, const float* __restrict__ enc_b1,
          const float* __restrict__ dec_b0, const float* __restrict__ dec_b1,
          const float* __restrict__ fc_W,  const float* __restrict__ fc_b,
          float* __restrict__ out)
{
  // h in B-frag layout: element (n,k) at n*S + ((k>>3)^(n&7))*8 + (k&7)
  __shared__ unsigned short h0h[NB*S0], h0l[NB*S0];
  __shared__ unsigned short h1h[NB*S1], h1l[NB*S1];
  __shared__ unsigned short xbh[NB*8],  xbl[NB*8];   // x / mu feedback (k=128..135), unswizzled
  __shared__ float bias[1024];                        // current phase: [b0 | b1]

  const int tid  = threadIdx.x;
  const int w    = tid>>6, l = tid&63;
  const int quad = (l>>4)&3, n15 = l&15, q7 = n15&7;
  const int b0   = blockIdx.x*NB;

  for (int i=tid;i<512;i+=TPB){ bias[i]=enc_b0[i]; bias[512+i]=enc_b1[i]; }
  for (int i=tid;i<NB*S0;i+=TPB){ h0h[i]=0; h0l[i]=0; h1h[i]=0; h1l[i]=0; }
  xbh[tid]=0; xbl[tid]=0;                    // NB*8 == 256 == TPB
  __syncthreads();

  auto write_x = [&](int t){
    if (tid < 96){
      const int n = tid & 31, c = tid >> 5;
      const float v = x[(size_t)(b0+n)*90 + t*3 + c];
      const unsigned short hi = f2bf(v);
      xbh[n*8+c] = hi; xbl[n*8+c] = f2bf(v - bf2f(hi));
    }
  };
  write_x(0);
  __syncthreads();

  // wave w owns m-tiles mt = g*8 + w*2 + s  (g=gate, s=0,1), i.e. j in [32w,32w+32)
  floatx4 acc[8][2];                 // [g*2+s][nt]
  float c0[2][2][4], c1[2][2][4];    // [s][nt][r]
#pragma unroll
  for (int s=0;s<2;s++)
#pragma unroll
    for (int nt=0;nt<2;nt++)
#pragma unroll
      for (int r=0;r<4;r++){ c0[s][nt][r]=0.f; c1[s][nt][r]=0.f; }

  auto zacc = [&]{
    const floatx4 z = {0.f,0.f,0.f,0.f};
#pragma unroll
    for (int p=0;p<8;p++){ acc[p][0]=z; acc[p][1]=z; }
  };

  // acc += A(kt range) * B(kb = kt-kboff blocks of Bh/Bl)
  auto mv = [&](const unsigned short* __restrict__ Ahi,
                const unsigned short* __restrict__ Alo, int KT,
                int k0, int k1, int kboff,
                const unsigned short* Bh, const unsigned short* Bl, int SS){
#pragma unroll 1
    for (int kt=k0; kt<k1; ++kt){
      const int bo = ((((kt-kboff)*4+quad)^q7)<<3);
      short8 bh[2], bl[2];
#pragma unroll
      for (int nt=0;nt<2;nt++){
        const int ro = (nt*16+n15)*SS + bo;
        bh[nt] = *(const short8*)(Bh + ro);
        bl[nt] = *(const short8*)(Bl + ro);
      }
#pragma unroll
      for (int p=0;p<8;p++){
        const int mt = (p>>1)*8 + w*2 + (p&1);
        const int ao = ((mt*KT + kt)*64 + l)*8;
        const short8 ah = *(const short8*)(Ahi + ao);
        const short8 al = *(const short8*)(Alo + ao);
        acc[p][0] = __builtin_amdgcn_mfma_f32_16x16x32_bf16(ah, bh[0], acc[p][0],0,0,0);
        acc[p][1] = __builtin_amdgcn_mfma_f32_16x16x32_bf16(ah, bh[1], acc[p][1],0,0,0);
        acc[p][0] = __builtin_amdgcn_mfma_f32_16x16x32_bf16(ah, bl[0], acc[p][0],0,0,0);
        acc[p][1] = __builtin_amdgcn_mfma_f32_16x16x32_bf16(ah, bl[1], acc[p][1],0,0,0);
        acc[p][0] = __builtin_amdgcn_mfma_f32_16x16x32_bf16(al, bh[0], acc[p][0],0,0,0);
        acc[p][1] = __builtin_amdgcn_mfma_f32_16x16x32_bf16(al, bh[1], acc[p][1],0,0,0);
      }
    }
  };

  // kt=4 of layer 0: B comes from xbuf (k=128..135; real data k<131, quad 0 only)
  auto mv_x = [&](const unsigned short* __restrict__ Ahi,
                  const unsigned short* __restrict__ Alo){
    const short8 z8 = {0,0,0,0,0,0,0,0};
    short8 bh[2]={z8,z8}, bl[2]={z8,z8};
    if (quad==0){
#pragma unroll
      for (int nt=0;nt<2;nt++){
        const int ro = (nt*16+n15)*8;
        bh[nt] = *(const short8*)(xbh + ro);
        bl[nt] = *(const short8*)(xbl + ro);
      }
    }
#pragma unroll
    for (int p=0;p<8;p++){
      const int mt = (p>>1)*8 + w*2 + (p&1);
      const int ao = ((mt*5 + 4)*64 + l)*8;
      const short8 ah = *(const short8*)(Ahi + ao);
      const short8 al = *(const short8*)(Alo + ao);
      acc[p][0] = __builtin_amdgcn_mfma_f32_16x16x32_bf16(ah, bh[0], acc[p][0],0,0,0);
      acc[p][1] = __builtin_amdgcn_mfma_f32_16x16x32_bf16(ah, bh[1], acc[p][1],0,0,0);
      acc[p][0] = __builtin_amdgcn_mfma_f32_16x16x32_bf16(ah, bl[0], acc[p][0],0,0,0);
      acc[p][1] = __builtin_amdgcn_mfma_f32_16x16x32_bf16(ah, bl[1], acc[p][1],0,0,0);
      acc[p][0] = __builtin_amdgcn_mfma_f32_16x16x32_bf16(al, bh[0], acc[p][0],0,0,0);
      acc[p][1] = __builtin_amdgcn_mfma_f32_16x16x32_bf16(al, bh[1], acc[p][1],0,0,0);
    }
  };

  // activations in-register; barrier, then packed b64 h-writes
  auto cell_update = [&](float (&cst)[2][2][4], int boff,
                         unsigned short* Hh, unsigned short* Hl, int SS){
    float hv[2][2][4];
#pragma unroll
    for (int s=0;s<2;s++)
#pragma unroll
      for (int nt=0;nt<2;nt++)
#pragma unroll
        for (int r=0;r<4;r++){
          const int j = (w*2+s)*16 + quad*4 + r;
          const float i_ = sigm(acc[0+s][nt][r]      + bias[boff       + j]);
          const float f_ = sigm(acc[2+s][nt][r]      + bias[boff + 128 + j]);
          const float g_ = tanh_fast(acc[4+s][nt][r] + bias[boff + 256 + j]);
          const float o_ = sigm(acc[6+s][nt][r]      + bias[boff + 384 + j]);
          const float c  = f_*cst[s][nt][r] + i_*g_;
          cst[s][nt][r] = c;
          hv[s][nt][r]  = o_*tanh_fast(c);
        }
    __syncthreads();                 // all waves done READING old h
#pragma unroll
    for (int s=0;s<2;s++)
#pragma unroll
      for (int nt=0;nt<2;nt++){
        const int jb = (w*2+s)*2 + (quad>>1);        // j>>3
        const int n  = nt*16 + n15;
        const int base = n*SS + ((jb ^ (n&7))<<3) + ((quad&1)<<2);
        ushort4v ph, pl;
#pragma unroll
        for (int r=0;r<4;r++){
          const unsigned short hi = f2bf(hv[s][nt][r]);
          ph[r] = hi;
          pl[r] = f2bf(hv[s][nt][r] - bf2f(hi));
        }
        *(ushort4v*)(Hh + base) = ph;                // ds_write_b64
        *(ushort4v*)(Hl + base) = pl;
      }
  };
  // NOTE: acc index map in cell_update: p = g*2+s with g blocks at p={0,1|2,3|4,5|6,7}

  // -------------------- encoder --------------------
#pragma unroll 1
  for (int t=0; t<TSTEPS; ++t){
    zacc();
    mv(wf+ENC0_HI, wf+ENC0_LO, 5, 0, 4, 0, h0h, h0l, S0);
    mv_x(wf+ENC0_HI, wf+ENC0_LO);
    cell_update(c0, 0, h0h, h0l, S0);
    if (t+1 < TSTEPS) write_x(t+1);      // xbuf disjoint from h writes
    __syncthreads();
    zacc();
    mv(wf+ENC1_HI, wf+ENC1_LO, 8, 0, 4, 0, h0h, h0l, S0);
    mv(wf+ENC1_HI, wf+ENC1_LO, 8, 4, 8, 4, h1h, h1l, S1);
    cell_update(c1, 512, h1h, h1l, S1);
    __syncthreads();
  }
  // xbuf still holds x[:,29,:] == decoder's initial input

  // ---- phase switch: dec biases into LDS; fcW A-frags (hi/lo) into regs ----
  for (int i=tid;i<512;i+=TPB){ bias[i]=dec_b0[i]; bias[512+i]=dec_b1[i]; }
  short8 fch[4], fcl[4];
  float  myfcb[4];
  if (w < 2){
#pragma unroll
    for (int kt=0;kt<4;kt++){
      const int kb = kt*32 + quad*8;
#pragma unroll
      for (int jj=0;jj<8;jj++){
        const float f = (n15<6) ? fc_W[n15*HID + kb + jj] : 0.f;  // A row = l&15
        const unsigned short hi = f2bf(f);
        fch[kt][jj] = (short)hi;
        fcl[kt][jj] = (short)f2bf(f - bf2f(hi));
      }
    }
#pragma unroll
    for (int r=0;r<4;r++){
      const int oi = quad*4 + r;
      myfcb[r] = (oi<6) ? fc_b[oi] : 0.f;
    }
  }
  __syncthreads();

  // -------------------- decoder --------------------
#pragma unroll 1
  for (int t=0; t<TSTEPS; ++t){
    zacc();
    mv(wf+DEC0_HI, wf+DEC0_LO, 5, 0, 4, 0, h0h, h0l, S0);
    mv_x(wf+DEC0_HI, wf+DEC0_LO);
    cell_update(c0, 0, h0h, h0l, S0);
    __syncthreads();
    zacc();
    mv(wf+DEC1_HI, wf+DEC1_LO, 8, 0, 4, 0, h0h, h0l, S0);
    mv(wf+DEC1_HI, wf+DEC1_LO, 8, 4, 8, 4, h1h, h1l, S1);
    cell_update(c1, 512, h1h, h1l, S1);
    __syncthreads();

    // FC head via MFMA: wave w<2 handles nt=w (rows w*16..w*16+15)
    // C layout: col=lane&15 -> n, row=quad*4+r -> oi (0..5 used)
    if (w < 2){
      floatx4 fa = {0.f,0.f,0.f,0.f};
#pragma unroll
      for (int kt=0;kt<4;kt++){
        const int bo = (((kt*4+quad)^q7)<<3);
        const int ro = (w*16+n15)*S1 + bo;
        const short8 bh = *(const short8*)(h1h + ro);
        const short8 bl = *(const short8*)(h1l + ro);
        fa = __builtin_amdgcn_mfma_f32_16x16x32_bf16(fch[kt], bh, fa,0,0,0);
        fa = __builtin_amdgcn_mfma_f32_16x16x32_bf16(fch[kt], bl, fa,0,0,0);
        fa = __builtin_amdgcn_mfma_f32_16x16x32_bf16(fcl[kt], bh, fa,0,0,0);
      }
      const int n = w*16 + n15;
      const size_t off = (size_t)(b0+n)*90 + (size_t)t*3;
      if (quad == 0){
#pragma unroll
        for (int r=0;r<4;r++){
          const float s = fa[r] + myfcb[r];
          if (r < 3){
            out[off + r] = s;                         // mu
            const unsigned short hi = f2bf(s);        // feed mu back as next x
            xbh[n*8+r] = hi; xbl[n*8+r] = f2bf(s - bf2f(hi));
          } else {
            out[MU_OFF + off] = s;                    // logvar[0]
          }
        }
      } else if (quad == 1){
#pragma unroll
        for (int r=0;r<2;r++)
          out[MU_OFF + off + 1 + r] = fa[r] + myfcb[r];  // logvar[1,2]
      }
    }
    __syncthreads();
  }
}

extern "C" void kernel_launch(void* const* d_in, const int* in_sizes, int n_in,
                              void* d_out, int out_size, void* d_ws, size_t ws_size,
                              hipStream_t stream) {
  const float* x        = (const float*)d_in[0];
  const float* enc_Wih0 = (const float*)d_in[1];
  const float* enc_Whh0 = (const float*)d_in[2];
  const float* enc_b0   = (const float*)d_in[3];
  const float* enc_Wih1 = (const float*)d_in[4];
  const float* enc_Whh1 = (const float*)d_in[5];
  const float* enc_b1   = (const float*)d_in[6];
  const float* dec_Wih0 = (const float*)d_in[7];
  const float* dec_Whh0 = (const float*)d_in[8];
  const float* dec_b0   = (const float*)d_in[9];
  const float* dec_Wih1 = (const float*)d_in[10];
  const float* dec_Whh1 = (const float*)d_in[11];
  const float* dec_b1   = (const float*)d_in[12];
  const float* fc_W     = (const float*)d_in[13];
  const float* fc_b     = (const float*)d_in[14];
  unsigned short* ws = (unsigned short*)d_ws;
  float* out = (float*)d_out;

  // 425,984 (hi,lo) pairs -> exactly 1664 blocks of 256
  prep_frag<<<1664, 256, 0, stream>>>(
      enc_Wih0, enc_Whh0, enc_Wih1, enc_Whh1,
      dec_Wih0, dec_Whh0, dec_Wih1, dec_Whh1, ws);

  lstm_mfma<<<NBLK, TPB, 0, stream>>>(
      x, ws, enc_b0, enc_b1, dec_b0, dec_b1, fc_W, fc_b, out);
}

// Round 2
// 4297.085 us; speedup vs baseline: 1.6909x; 1.6909x over previous
//
#include <hip/hip_runtime.h>
#include <cstdint>

typedef short short8  __attribute__((ext_vector_type(8)));
typedef unsigned short ushort4v __attribute__((ext_vector_type(4)));
typedef float floatx4 __attribute__((ext_vector_type(4)));

#define HID    128
#define NB     64
#define TPB    512
#define NBLK   1024          // 65536 / 64
#define TSTEPS 30
#define MU_OFF 5898240       // 65536*30*3

// ws layout (bf16 units): A-fragment-swizzled weight arrays, hi then lo per set
#define L0_SZ  81920         // 512*160  (K-ext: [Whh(128)|Wih0(3)|0(29)])
#define L1_SZ  131072        // 512*256  (K-ext: [Wih1(128)|Whh1(128)])
#define ENC0_HI 0
#define ENC0_LO 81920
#define ENC1_HI 163840
#define ENC1_LO 294912
#define DEC0_HI 425984
#define DEC0_LO 507904
#define DEC1_HI 589824
#define DEC1_LO 720896

#define S0 128               // h0 row stride (bf16): 16 k-blocks
#define S1 128               // h1 row stride: 16 k-blocks

// v_rcp_f32 (~1 ulp) instead of the IEEE div chain
__device__ __forceinline__ float sigm(float v){
  return __builtin_amdgcn_rcpf(1.f + __expf(-v));
}
__device__ __forceinline__ float tanh_fast(float v){
  return 2.f*__builtin_amdgcn_rcpf(1.f + __expf(-2.f*v)) - 1.f;
}

__device__ __forceinline__ unsigned short f2bf(float f){
  unsigned u = __float_as_uint(f);
  u = (u + 0x7FFF + ((u>>16)&1)) >> 16;     // RNE; inputs finite
  return (unsigned short)u;
}
__device__ __forceinline__ float bf2f(unsigned short b){
  return __uint_as_float(((unsigned)b)<<16);
}

// ---------------- prep: swizzle weights into A-fragment order, bf16 hi/lo ----
// A-frag element (mt, kt, lane l, jj):  A[mt*16 + (l&15)][kt*32 + ((l>>4)&3)*8 + jj]
// stored at ((mt*KT + kt)*64 + l)*8 + jj   -> consumer does 1 coalesced b128/lane
extern "C" __global__ void __launch_bounds__(256)
prep_frag(const float* __restrict__ eWih0, const float* __restrict__ eWhh0,
          const float* __restrict__ eWih1, const float* __restrict__ eWhh1,
          const float* __restrict__ dWih0, const float* __restrict__ dWhh0,
          const float* __restrict__ dWih1, const float* __restrict__ dWhh1,
          unsigned short* __restrict__ ws)
{
  const int idx = blockIdx.x*256 + threadIdx.x;   // one thread -> one (hi,lo) pair
  int i2, hi_base, lo_base, KT;
  const float* Wa; const float* Wb;
  if (idx < L0_SZ)                { i2=idx;                 hi_base=ENC0_HI; lo_base=ENC0_LO; Wa=eWhh0; Wb=eWih0; KT=5; }
  else if (idx < L0_SZ+L1_SZ)     { i2=idx-L0_SZ;           hi_base=ENC1_HI; lo_base=ENC1_LO; Wa=eWih1; Wb=eWhh1; KT=8; }
  else if (idx < 2*L0_SZ+L1_SZ)   { i2=idx-(L0_SZ+L1_SZ);   hi_base=DEC0_HI; lo_base=DEC0_LO; Wa=dWhh0; Wb=dWih0; KT=5; }
  else                            { i2=idx-(2*L0_SZ+L1_SZ); hi_base=DEC1_HI; lo_base=DEC1_LO; Wa=dWih1; Wb=dWhh1; KT=8; }
  const int jj = i2 & 7, l = (i2>>3)&63, tk = i2>>9;
  const int kt = (KT==5) ? (tk%5) : (tk&7);
  const int mt = (KT==5) ? (tk/5) : (tk>>3);
  const int row = mt*16 + (l&15);
  const int k   = kt*32 + ((l>>4)&3)*8 + jj;
  float w;
  if (KT==5) w = (k<128) ? Wa[row*128+k] : ((k<131) ? Wb[row*3 + (k-128)] : 0.f);
  else       w = (k<128) ? Wa[row*128+k] : Wb[row*128 + (k-128)];
  const unsigned short hi = f2bf(w);
  ws[hi_base + i2] = hi;
  ws[lo_base + i2] = f2bf(w - bf2f(hi));
}

// ------- fused LSTM: NB=64/block, 8 waves, 1 block/CU, no reg cap ----------
// wave w owns m-tile mt = g*8 + w for each gate g (rows j in [16w,16w+16))
extern "C" __global__ void __launch_bounds__(TPB, 2)
lstm_mfma(const float* __restrict__ x,
          const unsigned short* __restrict__ wf,
          const float* __restrict__ enc_b0, const float* __restrict__ enc_b1,
          const float* __restrict__ dec_b0, const float* __restrict__ dec_b1,
          const float* __restrict__ fc_W,  const float* __restrict__ fc_b,
          float* __restrict__ out)
{
  // h in B-frag layout: element (n,k) at n*S + ((k>>3)^(n&7))*8 + (k&7)
  __shared__ unsigned short h0h[NB*S0], h0l[NB*S0];
  __shared__ unsigned short h1h[NB*S1], h1l[NB*S1];
  __shared__ unsigned short xbh[NB*8],  xbl[NB*8];   // x / mu feedback, unswizzled
  __shared__ float bias[1024];                        // current phase: [b0 | b1]

  const int tid  = threadIdx.x;
  const int w    = tid>>6, l = tid&63;
  const int quad = (l>>4)&3, n15 = l&15, q7 = n15&7;
  const int b0   = blockIdx.x*NB;

  if (tid < 512){ bias[tid] = enc_b0[tid&511]*0.f + ((tid<512)?enc_b0[tid]:0.f); }
  // (simple init below instead)
  if (tid < 512) bias[tid] = enc_b0[tid];
  for (int i=tid;i<512;i+=TPB) bias[512+i] = enc_b1[i];
  for (int i=tid;i<NB*S0;i+=TPB){ h0h[i]=0; h0l[i]=0; h1h[i]=0; h1l[i]=0; }
  if (tid < NB*8){ xbh[tid]=0; xbl[tid]=0; }         // NB*8 == 512 == TPB
  __syncthreads();

  auto write_x = [&](int t){
    if (tid < 192){
      const int n = tid & 63, c = tid >> 6;
      const float v = x[(size_t)(b0+n)*90 + t*3 + c];
      const unsigned short hi = f2bf(v);
      xbh[n*8+c] = hi; xbl[n*8+c] = f2bf(v - bf2f(hi));
    }
  };
  write_x(0);
  __syncthreads();

  floatx4 acc[4][4];                 // [gate][nt]
  float c0[4][4], c1[4][4];          // [nt][r]
#pragma unroll
  for (int nt=0;nt<4;nt++)
#pragma unroll
    for (int r=0;r<4;r++){ c0[nt][r]=0.f; c1[nt][r]=0.f; }

  auto zacc = [&]{
    const floatx4 z = {0.f,0.f,0.f,0.f};
#pragma unroll
    for (int g=0;g<4;g++)
#pragma unroll
      for (int nt=0;nt<4;nt++) acc[g][nt]=z;
  };

  // acc += A(kt range) * B(kb = kt-kboff blocks of Bh/Bl)
  auto mv = [&](const unsigned short* __restrict__ Ahi,
                const unsigned short* __restrict__ Alo, int KT,
                int k0, int k1, int kboff,
                const unsigned short* Bh, const unsigned short* Bl, int SS){
#pragma unroll 1
    for (int kt=k0; kt<k1; ++kt){
      const int bo = ((((kt-kboff)*4+quad)^q7)<<3);
      short8 bh[4], bl[4];
#pragma unroll
      for (int nt=0;nt<4;nt++){
        const int ro = (nt*16+n15)*SS + bo;
        bh[nt] = *(const short8*)(Bh + ro);
        bl[nt] = *(const short8*)(Bl + ro);
      }
#pragma unroll
      for (int g=0;g<4;g++){
        const int mt = g*8 + w;
        const int ao = ((mt*KT + kt)*64 + l)*8;
        const short8 ah = *(const short8*)(Ahi + ao);
        const short8 al = *(const short8*)(Alo + ao);
#pragma unroll
        for (int nt=0;nt<4;nt++){
          acc[g][nt] = __builtin_amdgcn_mfma_f32_16x16x32_bf16(ah, bh[nt], acc[g][nt],0,0,0);
          acc[g][nt] = __builtin_amdgcn_mfma_f32_16x16x32_bf16(ah, bl[nt], acc[g][nt],0,0,0);
          acc[g][nt] = __builtin_amdgcn_mfma_f32_16x16x32_bf16(al, bh[nt], acc[g][nt],0,0,0);
        }
      }
    }
  };

  // kt=4 of layer 0: B comes from xbuf (k=128..135; real data k<131, quad 0 only)
  auto mv_x = [&](const unsigned short* __restrict__ Ahi,
                  const unsigned short* __restrict__ Alo){
    const short8 z8 = {0,0,0,0,0,0,0,0};
    short8 bh[4]={z8,z8,z8,z8}, bl[4]={z8,z8,z8,z8};
    if (quad==0){
#pragma unroll
      for (int nt=0;nt<4;nt++){
        const int ro = (nt*16+n15)*8;
        bh[nt] = *(const short8*)(xbh + ro);
        bl[nt] = *(const short8*)(xbl + ro);
      }
    }
#pragma unroll
    for (int g=0;g<4;g++){
      const int mt = g*8 + w;
      const int ao = ((mt*5 + 4)*64 + l)*8;
      const short8 ah = *(const short8*)(Ahi + ao);
      const short8 al = *(const short8*)(Alo + ao);
#pragma unroll
      for (int nt=0;nt<4;nt++){
        acc[g][nt] = __builtin_amdgcn_mfma_f32_16x16x32_bf16(ah, bh[nt], acc[g][nt],0,0,0);
        acc[g][nt] = __builtin_amdgcn_mfma_f32_16x16x32_bf16(ah, bl[nt], acc[g][nt],0,0,0);
        acc[g][nt] = __builtin_amdgcn_mfma_f32_16x16x32_bf16(al, bh[nt], acc[g][nt],0,0,0);
      }
    }
  };

  // activations in-register; barrier, then packed b64 h-writes
  auto cell_update = [&](float (&cst)[4][4], int boff,
                         unsigned short* Hh, unsigned short* Hl, int SS){
    float hv[4][4];
#pragma unroll
    for (int nt=0;nt<4;nt++)
#pragma unroll
      for (int r=0;r<4;r++){
        const int j = w*16 + quad*4 + r;
        const float i_ = sigm(acc[0][nt][r]      + bias[boff       + j]);
        const float f_ = sigm(acc[1][nt][r]      + bias[boff + 128 + j]);
        const float g_ = tanh_fast(acc[2][nt][r] + bias[boff + 256 + j]);
        const float o_ = sigm(acc[3][nt][r]      + bias[boff + 384 + j]);
        const float c  = f_*cst[nt][r] + i_*g_;
        cst[nt][r] = c;
        hv[nt][r]  = o_*tanh_fast(c);
      }
    __syncthreads();                 // all waves done READING old h
#pragma unroll
    for (int nt=0;nt<4;nt++){
      const int jb = w*2 + (quad>>1);              // j>>3
      const int n  = nt*16 + n15;
      const int base = n*SS + ((jb ^ (n&7))<<3) + ((quad&1)<<2);
      ushort4v ph, pl;
#pragma unroll
      for (int r=0;r<4;r++){
        const unsigned short hi = f2bf(hv[nt][r]);
        ph[r] = hi;
        pl[r] = f2bf(hv[nt][r] - bf2f(hi));
      }
      *(ushort4v*)(Hh + base) = ph;                // ds_write_b64
      *(ushort4v*)(Hl + base) = pl;
    }
  };

  // -------------------- encoder --------------------
#pragma unroll 1
  for (int t=0; t<TSTEPS; ++t){
    zacc();
    mv(wf+ENC0_HI, wf+ENC0_LO, 5, 0, 4, 0, h0h, h0l, S0);
    mv_x(wf+ENC0_HI, wf+ENC0_LO);
    cell_update(c0, 0, h0h, h0l, S0);
    if (t+1 < TSTEPS) write_x(t+1);      // xbuf disjoint from h writes
    __syncthreads();
    zacc();
    mv(wf+ENC1_HI, wf+ENC1_LO, 8, 0, 4, 0, h0h, h0l, S0);
    mv(wf+ENC1_HI, wf+ENC1_LO, 8, 4, 8, 4, h1h, h1l, S1);
    cell_update(c1, 512, h1h, h1l, S1);
    __syncthreads();
  }
  // xbuf still holds x[:,29,:] == decoder's initial input

  // ---- phase switch: dec biases into LDS; fcW A-frags (hi/lo) into regs ----
  if (tid < 512) bias[tid] = dec_b0[tid];
  for (int i=tid;i<512;i+=TPB) bias[512+i] = dec_b1[i];
  short8 fch[4], fcl[4];
  float  myfcb[4];
  if (w < 4){
#pragma unroll
    for (int kt=0;kt<4;kt++){
      const int kb = kt*32 + quad*8;
#pragma unroll
      for (int jj=0;jj<8;jj++){
        const float f = (n15<6) ? fc_W[n15*HID + kb + jj] : 0.f;  // A row = l&15
        const unsigned short hi = f2bf(f);
        fch[kt][jj] = (short)hi;
        fcl[kt][jj] = (short)f2bf(f - bf2f(hi));
      }
    }
#pragma unroll
    for (int r=0;r<4;r++){
      const int oi = quad*4 + r;
      myfcb[r] = (oi<6) ? fc_b[oi] : 0.f;
    }
  }
  __syncthreads();

  // -------------------- decoder --------------------
#pragma unroll 1
  for (int t=0; t<TSTEPS; ++t){
    zacc();
    mv(wf+DEC0_HI, wf+DEC0_LO, 5, 0, 4, 0, h0h, h0l, S0);
    mv_x(wf+DEC0_HI, wf+DEC0_LO);
    cell_update(c0, 0, h0h, h0l, S0);
    __syncthreads();
    zacc();
    mv(wf+DEC1_HI, wf+DEC1_LO, 8, 0, 4, 0, h0h, h0l, S0);
    mv(wf+DEC1_HI, wf+DEC1_LO, 8, 4, 8, 4, h1h, h1l, S1);
    cell_update(c1, 512, h1h, h1l, S1);
    __syncthreads();

    // FC head via MFMA: wave w<4 handles rows n = w*16 .. w*16+15
    // C layout: col=lane&15 -> n, row=quad*4+r -> oi (0..5 used)
    if (w < 4){
      floatx4 fa = {0.f,0.f,0.f,0.f};
#pragma unroll
      for (int kt=0;kt<4;kt++){
        const int bo = (((kt*4+quad)^q7)<<3);
        const int ro = (w*16+n15)*S1 + bo;
        const short8 bh = *(const short8*)(h1h + ro);
        const short8 bl = *(const short8*)(h1l + ro);
        fa = __builtin_amdgcn_mfma_f32_16x16x32_bf16(fch[kt], bh, fa,0,0,0);
        fa = __builtin_amdgcn_mfma_f32_16x16x32_bf16(fch[kt], bl, fa,0,0,0);
        fa = __builtin_amdgcn_mfma_f32_16x16x32_bf16(fcl[kt], bh, fa,0,0,0);
      }
      const int n = w*16 + n15;
      const size_t off = (size_t)(b0+n)*90 + (size_t)t*3;
      if (quad == 0){
#pragma unroll
        for (int r=0;r<4;r++){
          const float s = fa[r] + myfcb[r];
          if (r < 3){
            out[off + r] = s;                         // mu
            const unsigned short hi = f2bf(s);        // feed mu back as next x
            xbh[n*8+r] = hi; xbl[n*8+r] = f2bf(s - bf2f(hi));
          } else {
            out[MU_OFF + off] = s;                    // logvar[0]
          }
        }
      } else if (quad == 1){
#pragma unroll
        for (int r=0;r<2;r++)
          out[MU_OFF + off + 1 + r] = fa[r] + myfcb[r];  // logvar[1,2]
      }
    }
    __syncthreads();
  }
}

extern "C" void kernel_launch(void* const* d_in, const int* in_sizes, int n_in,
                              void* d_out, int out_size, void* d_ws, size_t ws_size,
                              hipStream_t stream) {
  const float* x        = (const float*)d_in[0];
  const float* enc_Wih0 = (const float*)d_in[1];
  const float* enc_Whh0 = (const float*)d_in[2];
  const float* enc_b0   = (const float*)d_in[3];
  const float* enc_Wih1 = (const float*)d_in[4];
  const float* enc_Whh1 = (const float*)d_in[5];
  const float* enc_b1   = (const float*)d_in[6];
  const float* dec_Wih0 = (const float*)d_in[7];
  const float* dec_Whh0 = (const float*)d_in[8];
  const float* dec_b0   = (const float*)d_in[9];
  const float* dec_Wih1 = (const float*)d_in[10];
  const float* dec_Whh1 = (const float*)d_in[11];
  const float* dec_b1   = (const float*)d_in[12];
  const float* fc_W     = (const float*)d_in[13];
  const float* fc_b     = (const float*)d_in[14];
  unsigned short* ws = (unsigned short*)d_ws;
  float* out = (float*)d_out;

  // 425,984 (hi,lo) pairs -> exactly 1664 blocks of 256
  prep_frag<<<1664, 256, 0, stream>>>(
      enc_Wih0, enc_Whh0, enc_Wih1, enc_Whh1,
      dec_Wih0, dec_Whh0, dec_Wih1, dec_Whh1, ws);

  lstm_mfma<<<NBLK, TPB, 0, stream>>>(
      x, ws, enc_b0, enc_b1, dec_b0, dec_b1, fc_W, fc_b, out);
}